// Round 10
// baseline (252.215 us; speedup 1.0000x reference)
//
#include <hip/hip_runtime.h>
#include <math.h>

// MS-SSIM loss, 5 levels, 11-tap separable Gaussian (sigma=1.5), VALID padding.
// Round 10: round-8 double-buffered row-streaming, widened to 4 input rows per
// iteration: barriers & vmcnt waits per row halved, prefetch distance doubled,
// ring shift amortized (10 movs/row), 4 independent h-conv chains for ILP.
// Interleaved {a,b} float2 LDS (1 ds_read_b64 per tap), 14-deep shift ring,
// x2-rescaled emit algebra. 4-map transform (a=x+y, b=x-y) as rounds 4-8.

#define RWF 272          // staged float-cols per row: 256 band + 10 halo + pad

struct GWin { float w[11]; };

__global__ __launch_bounds__(256)
void ssim_rows_kernel(const float* __restrict__ X, const float* __restrict__ Y,
                      float* __restrict__ poolX, float* __restrict__ poolY,
                      float* __restrict__ accum,   // [0..95]=ssim, [96..191]=cs
                      int S, int outS, int doPool, int rps, GWin gw)
{
    __shared__ float2 ab[2][4][RWF];     // [slot][row 0..3][floatcol] = {a, b}
    __shared__ float rs[4], rc[4];

    const int ch  = blockIdx.z;
    const int oy0 = blockIdx.x * rps;
    const int cb0 = blockIdx.y * 256;
    const int tid = threadIdx.x;
    const int halfS = S >> 1;

    int rowsOut = outS - oy0; if (rowsOut > rps) rowsOut = rps;
    const int NIT = (rowsOut + 13) >> 2;     // iterations, 4 input rows each

    const float* Xc = X + (size_t)ch * S * S;
    const float* Yc = Y + (size_t)ch * S * S;

    // staging decode: 544 float2-col tasks over 4 rows (136 per row)
    const int ta = tid,       ra_ = ta / 136,  ca_ = ta - 136 * ra_;
    const int tb = tid + 256, rb_ = tb / 136,  cbb = tb - 136 * rb_;
    const int tc = tid + 512, rc_ = tc / 136,  ccc = tc - 136 * rc_;
    const bool hasC = (tid < 32);

    float2 sxa, sya, sxb, syb, sxc, syc;     // prefetched global data

    auto ld1 = [&](int baseRow, int r, int c2, float2& sx, float2& sy) {
        int gr = baseRow + r; if (gr > S - 1) gr = S - 1;
        const float* xr = Xc + (size_t)gr * S;
        const float* yr = Yc + (size_t)gr * S;
        int gc = cb0 + 2 * c2;
        if (gc + 1 < S) {
            sx = *reinterpret_cast<const float2*>(xr + gc);
            sy = *reinterpret_cast<const float2*>(yr + gc);
        } else {
            int g0 = gc < S ? gc : S - 1;
            sx.x = xr[g0]; sx.y = xr[S - 1];
            sy.x = yr[g0]; sy.y = yr[S - 1];
        }
    };
    auto issue = [&](int baseRow) {
        ld1(baseRow, ra_, ca_, sxa, sya);
        ld1(baseRow, rb_, cbb, sxb, syb);
        if (hasC) ld1(baseRow, rc_, ccc, sxc, syc);
    };
    auto write_slot = [&](int sl) {          // {a,b} interleaved, 1 b128 per task
        float4 v;
        v.x = sxa.x + sya.x; v.y = sxa.x - sya.x;
        v.z = sxa.y + sya.y; v.w = sxa.y - sya.y;
        *reinterpret_cast<float4*>(&ab[sl][ra_][2 * ca_]) = v;
        v.x = sxb.x + syb.x; v.y = sxb.x - syb.x;
        v.z = sxb.y + syb.y; v.w = sxb.y - syb.y;
        *reinterpret_cast<float4*>(&ab[sl][rb_][2 * cbb]) = v;
        if (hasC) {
            v.x = sxc.x + syc.x; v.y = sxc.x - syc.x;
            v.z = sxc.y + syc.y; v.w = sxc.y - syc.y;
            *reinterpret_cast<float4*>(&ab[sl][rc_][2 * ccc]) = v;
        }
    };

    // pending v-conv partials: 14 slots x {P,Q} + {U,V}, float2-packed
    float2 pendPQ[14], pendUV[14];
    #pragma unroll
    for (int i = 0; i < 14; ++i) { pendPQ[i] = make_float2(0.f, 0.f); pendUV[i] = make_float2(0.f, 0.f); }

    float ssum = 0.f, csum = 0.f;
    const float C1x2 = 2e-4f, C2x2 = 1.8e-3f;
    const bool colOK = (cb0 + tid) < outS;

    // pool decode: 2 pooled rows x 128 cols per iter
    const int prp = tid >> 7, pcl = tid & 127;

    // prologue
    issue(oy0);
    write_slot(0);
    issue(oy0 + 4);
    __syncthreads();

    for (int k = 0; k < NIT; ++k) {
        const int sl = k & 1;
        if (k + 1 < NIT) {
            write_slot(sl ^ 1);              // rows 4(k+1).. (regs from iter k-1)
            if (k + 2 < NIT) issue(oy0 + 4 * (k + 2));
        }

        // ---- h-conv for 4 staged rows: one ds_read_b64 per tap ----
        float2 hPQ[4], hUV[4];
        #pragma unroll
        for (int r = 0; r < 4; ++r) {
            float2 pq = make_float2(0.f, 0.f), uv = make_float2(0.f, 0.f);
            #pragma unroll
            for (int t = 0; t < 11; ++t) {
                float wt = gw.w[t];
                float2 v = ab[sl][r][tid + t];
                pq.x = fmaf(wt, v.x, pq.x);
                pq.y = fmaf(wt, v.y, pq.y);
                uv.x = fmaf(wt * v.x, v.x, uv.x);
                uv.y = fmaf(wt * v.y, v.y, uv.y);
            }
            hPQ[r] = pq; hUV[r] = uv;
        }

        // ---- 2x2 pool (2 pooled rows per iter, all 256 threads) ----
        if (doPool && (2 * k + prp) < (rps >> 1)) {
            int pc = (cb0 >> 1) + pcl;
            if (pc < halfS) {
                float4 q0 = *reinterpret_cast<const float4*>(&ab[sl][2 * prp][2 * pcl]);
                float4 q1 = *reinterpret_cast<const float4*>(&ab[sl][2 * prp + 1][2 * pcl]);
                float sa = q0.x + q0.z + q1.x + q1.z;
                float sb = q0.y + q0.w + q1.y + q1.w;
                int prow = (oy0 >> 1) + 2 * k + prp;
                size_t o = (size_t)ch * halfS * halfS + (size_t)prow * halfS + pc;
                poolX[o] = 0.125f * (sa + sb);
                poolY[o] = 0.125f * (sa - sb);
            }
        }

        // ---- v-accumulate: input row 4k+r feeds slots j=r..r+10 with w[r+10-j] ----
        #pragma unroll
        for (int r = 0; r < 4; ++r) {
            #pragma unroll
            for (int j = r; j <= r + 10; ++j) {
                float wt = gw.w[r + 10 - j];
                pendPQ[j].x = fmaf(wt, hPQ[r].x, pendPQ[j].x);
                pendPQ[j].y = fmaf(wt, hPQ[r].y, pendPQ[j].y);
                pendUV[j].x = fmaf(wt, hUV[r].x, pendUV[j].x);
                pendUV[j].y = fmaf(wt, hUV[r].y, pendUV[j].y);
            }
        }

        // ---- emit 4 finished output rows: rel = 4k-10+e (x2-rescaled, exact) ----
        #pragma unroll
        for (int e = 0; e < 4; ++e) {
            int rel = 4 * k - 10 + e;
            float p = pendPQ[e].x, q = pendPQ[e].y;
            float u = pendUV[e].x, v = pendUV[e].y;
            float p2 = p * p, q2 = q * q;
            float A = p2 - q2;                         // 2*(2 mu12)
            float csn = (u - v - A) + C2x2;            // 2*(2 sigma12) + 2C2
            float csd = (u + v - p2 - q2) + C2x2;
            float cs  = csn * __builtin_amdgcn_rcpf(csd);
            float ss  = (A + C1x2) * __builtin_amdgcn_rcpf(p2 + q2 + C1x2) * cs;
            if ((unsigned)rel < (unsigned)rowsOut && colOK) { ssum += ss; csum += cs; }
        }

        // ---- shift ring by 4 slots ----
        #pragma unroll
        for (int j = 0; j < 10; ++j) { pendPQ[j] = pendPQ[j + 4]; pendUV[j] = pendUV[j + 4]; }
        #pragma unroll
        for (int j = 10; j < 14; ++j) { pendPQ[j] = make_float2(0.f, 0.f); pendUV[j] = make_float2(0.f, 0.f); }

        __syncthreads();
    }

    // ---- block reduction + atomic accumulate ----
    for (int off = 32; off > 0; off >>= 1) {
        ssum += __shfl_down(ssum, off);
        csum += __shfl_down(csum, off);
    }
    int wid = tid >> 6, lane = tid & 63;
    if (lane == 0) { rs[wid] = ssum; rc[wid] = csum; }
    __syncthreads();
    if (tid == 0) {
        float s = rs[0] + rs[1] + rs[2] + rs[3];
        float c = rc[0] + rc[1] + rc[2] + rc[3];
        atomicAdd(&accum[ch], s);
        atomicAdd(&accum[96 + ch], c);
    }
}

__global__ void finalize_kernel(const float* __restrict__ accum, float* __restrict__ out)
{
    __shared__ float red[2];
    const int t = threadIdx.x;   // 128 threads
    const float w[5]   = {0.0448f, 0.2856f, 0.3001f, 0.2363f, 0.1333f};
    const float inv[5] = {1.f / (502.f * 502.f), 1.f / (246.f * 246.f),
                          1.f / (118.f * 118.f), 1.f / (54.f * 54.f),
                          1.f / (22.f * 22.f)};
    float ms = 0.f;
    if (t < 96) {
        ms = 1.f;
        #pragma unroll
        for (int l = 0; l < 5; ++l) {
            float v = (l < 4) ? accum[l * 192 + 96 + t] : accum[l * 192 + t];
            v *= inv[l];
            v = fmaxf(v, 0.f);
            ms *= powf(v, w[l]);
        }
    }
    for (int off = 32; off > 0; off >>= 1) ms += __shfl_down(ms, off);
    int wid = t >> 6, lane = t & 63;
    if (lane == 0) red[wid] = ms;
    __syncthreads();
    if (t == 0) out[0] = 1.f - (red[0] + red[1]) * (1.f / 96.f);
}

extern "C" void kernel_launch(void* const* d_in, const int* in_sizes, int n_in,
                              void* d_out, int out_size, void* d_ws, size_t ws_size,
                              hipStream_t stream)
{
    (void)in_sizes; (void)n_in; (void)out_size; (void)ws_size;
    const float* X = (const float*)d_in[0];
    const float* Y = (const float*)d_in[1];
    float* out = (float*)d_out;
    float* ws  = (float*)d_ws;

    // Gaussian window (size 11, sigma 1.5), normalized
    GWin gw;
    {
        double g[11], s = 0.0;
        for (int i = 0; i < 11; ++i) { double d = i - 5; g[i] = exp(-(d * d) / 4.5); s += g[i]; }
        for (int i = 0; i < 11; ++i) gw.w[i] = (float)(g[i] / s);
    }

    // workspace layout (floats)
    float* accum = ws;                 // 5 levels * 192
    size_t off = 1024;
    float* p1x = ws + off; off += (size_t)96 * 256 * 256;
    float* p1y = ws + off; off += (size_t)96 * 256 * 256;
    float* p2x = ws + off; off += (size_t)96 * 128 * 128;
    float* p2y = ws + off; off += (size_t)96 * 128 * 128;
    float* p3x = ws + off; off += (size_t)96 * 64 * 64;
    float* p3y = ws + off; off += (size_t)96 * 64 * 64;
    float* p4x = ws + off; off += (size_t)96 * 32 * 32;
    float* p4y = ws + off; off += (size_t)96 * 32 * 32;

    hipMemsetAsync(accum, 0, 5 * 192 * sizeof(float), stream);

    auto launch = [&](const float* x, const float* y, float* px_, float* py_,
                      float* acc, int S, int outS, int pool) {
        int rps;
        if      (S >= 512) rps = 64;
        else if (S == 256) rps = 32;
        else if (S == 128) rps = 16;
        else if (S == 64)  rps = 16;
        else               rps = 32;
        dim3 g((outS + rps - 1) / rps, (S + 255) / 256, 96);
        ssim_rows_kernel<<<g, 256, 0, stream>>>(x, y, px_, py_, acc, S, outS, pool, rps, gw);
    };

    launch(X,   Y,   p1x, p1y, accum + 0,   512, 502, 1);
    launch(p1x, p1y, p2x, p2y, accum + 192, 256, 246, 1);
    launch(p2x, p2y, p3x, p3y, accum + 384, 128, 118, 1);
    launch(p3x, p3y, p4x, p4y, accum + 576, 64,  54,  1);
    launch(p4x, p4y, nullptr, nullptr, accum + 768, 32, 22, 0);

    finalize_kernel<<<1, 128, 0, stream>>>(accum, out);
}